// Round 4
// baseline (291.565 us; speedup 1.0000x reference)
//
#include <hip/hip_runtime.h>

#define NEG_SLOPE 0.2f

constexpr int N_NODES = 50000;
constexpr int TPB = 256;
constexpr int SCAN_CHUNK = 1024;

// ---------------------------------------------------------------------------
// One-shot W transpose: Wt[k4*OUTD + c] = float4(W[4k4..4k4+3][c]).
// Lets the GEMM read W as a single coalesced float4 per k4 (L1-resident).
// ---------------------------------------------------------------------------
__global__ void transpose_w4(const float* __restrict__ W,
                             float4* __restrict__ Wt, int K, int OUTD) {
  int i = blockIdx.x * blockDim.x + threadIdx.x;
  if (i >= (K / 4) * OUTD) return;
  int k4 = i / OUTD, c = i % OUTD;
  Wt[i] = make_float4(W[(4 * k4 + 0) * OUTD + c], W[(4 * k4 + 1) * OUTD + c],
                      W[(4 * k4 + 2) * OUTD + c], W[(4 * k4 + 3) * OUTD + c]);
}

// ---------------------------------------------------------------------------
// GEMM + fused alpha_src/alpha_dst epilogue. No LDS, no barriers.
// X: [n, K] row-major, Wt: [K/4][OUTD] float4 (pre-transposed).
// Thread t -> col = t % OUTD, row group t / OUTD; RPT=8 rows per thread.
// X loads are wave-uniform within a row group (hardware broadcast); W load
// is one coalesced float4 from L1 (W is 8-32 KB, hot in every CU's L1).
// ---------------------------------------------------------------------------
template <int K, int OUTD, int RPT>
__global__ __launch_bounds__(TPB) void gemm_alpha(
    const float* __restrict__ X, const float4* __restrict__ Wt,
    const float* __restrict__ avec_src, const float* __restrict__ avec_dst,
    float* __restrict__ Hout, float* __restrict__ as_out,
    float* __restrict__ ad_out, int n) {
  constexpr int RPG = TPB / OUTD;  // row groups per block
  constexpr int ROWS = RPG * RPT;  // rows per block
  const int t = threadIdx.x;
  const int col = t & (OUTD - 1);
  const int rg = t / OUTD;
  const int r0 = blockIdx.x * ROWS + rg * RPT;

  const float4* xrow[RPT];
#pragma unroll
  for (int q = 0; q < RPT; ++q)
    xrow[q] = (const float4*)(X + (size_t)min(r0 + q, n - 1) * K);

  const float a_s = avec_src[col];
  const float a_d = avec_dst[col];

  float acc[RPT];
#pragma unroll
  for (int q = 0; q < RPT; ++q) acc[q] = 0.f;

#pragma unroll 2
  for (int k4 = 0; k4 < K / 4; ++k4) {
    const float4 wv = Wt[k4 * OUTD + col];
#pragma unroll
    for (int q = 0; q < RPT; ++q) {
      const float4 xv = xrow[q][k4];  // broadcast within row group
      acc[q] = fmaf(xv.x, wv.x, acc[q]);
      acc[q] = fmaf(xv.y, wv.y, acc[q]);
      acc[q] = fmaf(xv.z, wv.z, acc[q]);
      acc[q] = fmaf(xv.w, wv.w, acc[q]);
    }
  }

#pragma unroll
  for (int q = 0; q < RPT; ++q) {
    const int r = r0 + q;
    if (r < n) {  // uniform within the OUTD-lane group
      Hout[(size_t)r * OUTD + col] = acc[q];
      float vs = acc[q] * a_s, vd = acc[q] * a_d;
#pragma unroll
      for (int m = OUTD / 2; m >= 1; m >>= 1) {
        vs += __shfl_xor(vs, m);
        vd += __shfl_xor(vd, m);
      }
      if (col == 0) {
        as_out[r] = vs;
        ad_out[r] = vd;
      }
    }
  }
}

// ---------------------------------------------------------------------------
// CSR-by-dst build: count -> 3-phase exclusive scan -> fill (stores SRC
// node id directly).
// ---------------------------------------------------------------------------
__global__ void count_edges(const int* __restrict__ edst, int E, int n,
                            int* __restrict__ cnt) {
  int i = blockIdx.x * blockDim.x + threadIdx.x;
  if (i >= E + n) return;
  int d = (i < E) ? edst[i] : (i - E);
  atomicAdd(&cnt[d], 1);
}

__global__ void scan_block_sums(const int* __restrict__ in, int n,
                                int* __restrict__ sums) {
  __shared__ int sdata[TPB];
  const int base = blockIdx.x * SCAN_CHUNK;
  int s = 0;
  for (int i = threadIdx.x; i < SCAN_CHUNK; i += TPB) {
    int idx = base + i;
    s += (idx < n) ? in[idx] : 0;
  }
  sdata[threadIdx.x] = s;
  __syncthreads();
  for (int m = TPB / 2; m >= 1; m >>= 1) {
    if (threadIdx.x < m) sdata[threadIdx.x] += sdata[threadIdx.x + m];
    __syncthreads();
  }
  if (threadIdx.x == 0) sums[blockIdx.x] = sdata[0];
}

__global__ void scan_sums_exclusive(int* __restrict__ sums, int nchunks,
                                    int* __restrict__ total) {
  if (blockIdx.x == 0 && threadIdx.x == 0) {
    int run = 0;
    for (int i = 0; i < nchunks; ++i) {
      int v = sums[i];
      sums[i] = run;
      run += v;
    }
    *total = run;
  }
}

__global__ void scan_write(const int* __restrict__ in, int n,
                           const int* __restrict__ chunkOff,
                           const int* __restrict__ total,
                           int* __restrict__ rowoff) {
  __shared__ int tsum[TPB];
  const int base = blockIdx.x * SCAN_CHUNK;
  const int t = threadIdx.x;
  int v[4];
  int s = 0;
#pragma unroll
  for (int j = 0; j < 4; ++j) {
    int idx = base + t * 4 + j;
    v[j] = (idx < n) ? in[idx] : 0;
    s += v[j];
  }
  tsum[t] = s;
  __syncthreads();
  for (int off = 1; off < TPB; off <<= 1) {  // Hillis-Steele inclusive
    int x = (t >= off) ? tsum[t - off] : 0;
    __syncthreads();
    tsum[t] += x;
    __syncthreads();
  }
  int excl = ((t == 0) ? 0 : tsum[t - 1]) + chunkOff[blockIdx.x];
#pragma unroll
  for (int j = 0; j < 4; ++j) {
    int idx = base + t * 4 + j;
    if (idx < n) rowoff[idx] = excl;
    excl += v[j];
  }
  if (blockIdx.x == 0 && t == 0) rowoff[n] = *total;
}

__global__ void fill_psrc(const int* __restrict__ esrc,
                          const int* __restrict__ edst, int E, int n,
                          int* __restrict__ cursor, int* __restrict__ psrc) {
  int i = blockIdx.x * blockDim.x + threadIdx.x;
  if (i >= E + n) return;
  int d, s;
  if (i < E) {
    d = edst[i];
    s = esrc[i];
  } else {
    d = i - E;
    s = i - E;
  }
  int pos = atomicAdd(&cursor[d], 1);
  psrc[pos] = s;
}

// ---------------------------------------------------------------------------
// GAT aggregation: one wave per destination node, single-pass online softmax.
// Per 64-edge chunk: lane l owns edge beg+c+l (parallel gathers of as[src]),
// wave-reduce chunk max & sum. The (w, src) pairs are parked in LDS as float2;
// the accumulation loop reads 1 pair per step per edge-phase (ds_read_b64
// broadcast) and gathers float2 of the H row: LPE = D/2 lanes per edge,
// EPS = 64/LPE edges per step. Edge-phase partials folded with shfl_xor.
// ---------------------------------------------------------------------------
template <int D>
__global__ __launch_bounds__(TPB) void gat_aggregate(
    const float* __restrict__ Hf, const float* __restrict__ as,
    const float* __restrict__ ad, const int* __restrict__ rowoff,
    const int* __restrict__ psrc, int n, const float* __restrict__ bias,
    float* __restrict__ out, int doRelu) {
  constexpr int LPE = D / 2;     // lanes per edge (float2 each)
  constexpr int EPS = 64 / LPE;  // edges per step
  constexpr int WPB = TPB / 64;  // waves per block
  __shared__ float2 wsP[WPB][64];

  const int wave = (blockIdx.x * blockDim.x + threadIdx.x) >> 6;
  const int wid = threadIdx.x >> 6;
  const int lane = threadIdx.x & 63;
  if (wave >= n) return;
  const int i = wave;
  const int beg = rowoff[i];
  const int end = rowoff[i + 1];
  const float adi = ad[i];

  const int p = lane / LPE;          // edge phase within a step
  const int fl2 = (lane % LPE) * 2;  // feature pair base

  float m = -1e30f, denom = 0.f;
  float2 acc = make_float2(0.f, 0.f);

  for (int c = beg; c < end; c += 64) {
    const int k = c + lane;
    const bool valid = (k < end);
    int s = 0;
    float e = -1e30f;
    if (valid) {
      s = psrc[k];
      e = as[s] + adi;
      e = (e > 0.f) ? e : e * NEG_SLOPE;
    }
    // chunk max over the wave
    float cm = e;
#pragma unroll
    for (int mm = 32; mm >= 1; mm >>= 1) cm = fmaxf(cm, __shfl_xor(cm, mm));
    const float nm = fmaxf(m, cm);
    const float scale = __expf(m - nm);  // first chunk: exp(-inf) = 0
    const float w = valid ? __expf(e - nm) : 0.f;
    float ws = w;
#pragma unroll
    for (int mm = 32; mm >= 1; mm >>= 1) ws += __shfl_xor(ws, mm);
    denom = denom * scale + ws;
    acc.x *= scale;
    acc.y *= scale;
    m = nm;

    wsP[wid][lane] = make_float2(w, __int_as_float(s));  // park (w, src)

    const int cnt = min(64, end - c);
    const int nsteps = (cnt + EPS - 1) / EPS;
#pragma unroll 4
    for (int j = 0; j < nsteps; ++j) {
      const float2 p2 = wsP[wid][j * EPS + p];
      const float wj = p2.x;
      const int sj = __float_as_int(p2.y);
      const float2 hv = *(const float2*)(Hf + (size_t)sj * D + fl2);
      acc.x = fmaf(wj, hv.x, acc.x);
      acc.y = fmaf(wj, hv.y, acc.y);
    }
  }
  // fold edge-phase partials
#pragma unroll
  for (int mm = LPE; mm < 64; mm <<= 1) {
    acc.x += __shfl_xor(acc.x, mm);
    acc.y += __shfl_xor(acc.y, mm);
  }
  if (lane < LPE) {
    float2 o;
    o.x = acc.x / denom + bias[fl2];
    o.y = acc.y / denom + bias[fl2 + 1];
    if (doRelu) {
      o.x = fmaxf(o.x, 0.f);
      o.y = fmaxf(o.y, 0.f);
    }
    *(float2*)(out + (size_t)i * D + fl2) = o;
  }
}

// ---------------------------------------------------------------------------
// Decode: logits[g] = dot(z[src], z[dst]) over 32 dims.
// 8 lanes per edge, float4 per lane (coalesced 128B per row).
// ---------------------------------------------------------------------------
__global__ __launch_bounds__(TPB) void decode_kernel(
    const float* __restrict__ z, const int* __restrict__ pos,
    const int* __restrict__ neg, int ED, float* __restrict__ out) {
  const int g = (blockIdx.x * blockDim.x + threadIdx.x) >> 3;
  const int lane = threadIdx.x & 7;
  if (g >= 2 * ED) return;
  int s, d;
  if (g < ED) {
    s = pos[g];
    d = pos[ED + g];
  } else {
    s = neg[g - ED];
    d = neg[ED + (g - ED)];
  }
  const float4 a = ((const float4*)(z + (size_t)s * 32))[lane];
  const float4 b = ((const float4*)(z + (size_t)d * 32))[lane];
  float v = a.x * b.x + a.y * b.y + a.z * b.z + a.w * b.w;
#pragma unroll
  for (int mm = 4; mm >= 1; mm >>= 1) v += __shfl_xor(v, mm);
  if (lane == 0) out[g] = v;
}

// ---------------------------------------------------------------------------
extern "C" void kernel_launch(void* const* d_in, const int* in_sizes, int n_in,
                              void* d_out, int out_size, void* d_ws,
                              size_t ws_size, hipStream_t stream) {
  const int N = N_NODES;
  const float* x = (const float*)d_in[0];
  const int* ei = (const int*)d_in[1];
  const int* pe = (const int*)d_in[2];
  const int* ne = (const int*)d_in[3];
  const float* W1 = (const float*)d_in[4];
  const float* a_src1 = (const float*)d_in[5];
  const float* a_dst1 = (const float*)d_in[6];
  const float* b1 = (const float*)d_in[7];
  const float* W2 = (const float*)d_in[8];
  const float* a_src2 = (const float*)d_in[9];
  const float* a_dst2 = (const float*)d_in[10];
  const float* b2 = (const float*)d_in[11];
  float* out = (float*)d_out;

  const int E = in_sizes[1] / 2;
  const int ED = in_sizes[2] / 2;
  const int* esrc = ei;
  const int* edst = ei + E;

  // workspace carve-out (256B aligned)
  char* base = (char*)d_ws;
  size_t off = 0;
  auto alloc = [&](size_t bytes) {
    char* p = base + off;
    off = (off + bytes + 255) & ~(size_t)255;
    return p;
  };
  float* A = (float*)alloc((size_t)N * 64 * 4);  // h1, later h2
  float* B = (float*)alloc((size_t)N * 64 * 4);  // out1, later z
  float* as1 = (float*)alloc((size_t)N * 4);
  float* ad1 = (float*)alloc((size_t)N * 4);
  float* as2 = (float*)alloc((size_t)N * 4);
  float* ad2 = (float*)alloc((size_t)N * 4);
  int* cnt = (int*)alloc((size_t)N * 4);  // counts, then cursor
  int* rowoff = (int*)alloc((size_t)(N + 1) * 4);
  int* chunkSums = (int*)alloc(64 * 4);
  int* total = (int*)alloc(4);
  int* psrc = (int*)alloc((size_t)(E + N) * 4);
  float4* Wt1 = (float4*)alloc((size_t)(128 / 4) * 64 * 16);
  float4* Wt2 = (float4*)alloc((size_t)(64 / 4) * 32 * 16);

  const int nEdgesTot = E + N;
  const int edgeBlocks = (nEdgesTot + TPB - 1) / TPB;
  const int nchunks = (N + SCAN_CHUNK - 1) / SCAN_CHUNK;

  // --- W pre-transpose (tiny, once) ---
  transpose_w4<<<(32 * 64 + TPB - 1) / TPB, TPB, 0, stream>>>(W1, Wt1, 128, 64);
  transpose_w4<<<(16 * 32 + TPB - 1) / TPB, TPB, 0, stream>>>(W2, Wt2, 64, 32);

  // --- CSR build (shared by both layers) ---
  hipMemsetAsync(cnt, 0, (size_t)N * 4, stream);
  count_edges<<<edgeBlocks, TPB, 0, stream>>>(edst, E, N, cnt);
  scan_block_sums<<<nchunks, TPB, 0, stream>>>(cnt, N, chunkSums);
  scan_sums_exclusive<<<1, 64, 0, stream>>>(chunkSums, nchunks, total);
  scan_write<<<nchunks, TPB, 0, stream>>>(cnt, N, chunkSums, total, rowoff);
  hipMemcpyAsync(cnt, rowoff, (size_t)N * 4, hipMemcpyDeviceToDevice, stream);
  fill_psrc<<<edgeBlocks, TPB, 0, stream>>>(esrc, edst, E, N, cnt, psrc);

  // --- layer 1: h1 = x@W1 (+alpha dots), aggregate (+b1, relu) ---
  {
    constexpr int ROWS = (TPB / 64) * 8;  // 32 rows/block
    gemm_alpha<128, 64, 8><<<(N + ROWS - 1) / ROWS, TPB, 0, stream>>>(
        x, Wt1, a_src1, a_dst1, A, as1, ad1, N);
  }
  gat_aggregate<64><<<(N + 3) / 4, TPB, 0, stream>>>(A, as1, ad1, rowoff, psrc,
                                                     N, b1, B, 1);

  // --- layer 2: h2 = out1@W2 (+alpha dots), aggregate (+b2) ---
  {
    constexpr int ROWS = (TPB / 32) * 8;  // 64 rows/block
    gemm_alpha<64, 32, 8><<<(N + ROWS - 1) / ROWS, TPB, 0, stream>>>(
        B, Wt2, a_src2, a_dst2, A, as2, ad2, N);
  }
  gat_aggregate<32><<<(N + 3) / 4, TPB, 0, stream>>>(A, as2, ad2, rowoff, psrc,
                                                     N, b2, B, 0);

  // --- decode ---
  const long long decThreads = 2LL * ED * 8;
  decode_kernel<<<(int)((decThreads + TPB - 1) / TPB), TPB, 0, stream>>>(
      B, pe, ne, ED, out);
}

// Round 5
// 246.624 us; speedup vs baseline: 1.1822x; 1.1822x over previous
//
#include <hip/hip_runtime.h>

#define NEG_SLOPE 0.2f

constexpr int N_NODES = 50000;
constexpr int TPB = 256;
constexpr int SCAN_CHUNK = 1024;

// ---------------------------------------------------------------------------
// One-shot W transpose: Wt[k4*OUTD + c] = float4(W[4k4..4k4+3][c]).
// ---------------------------------------------------------------------------
__global__ void transpose_w4(const float* __restrict__ W,
                             float4* __restrict__ Wt, int K, int OUTD) {
  int i = blockIdx.x * blockDim.x + threadIdx.x;
  if (i >= (K / 4) * OUTD) return;
  int k4 = i / OUTD, c = i % OUTD;
  Wt[i] = make_float4(W[(4 * k4 + 0) * OUTD + c], W[(4 * k4 + 1) * OUTD + c],
                      W[(4 * k4 + 2) * OUTD + c], W[(4 * k4 + 3) * OUTD + c]);
}

// ---------------------------------------------------------------------------
// GEMM + fused alpha epilogue. Wave-private double-buffered LDS pipeline,
// ZERO block barriers (no vmcnt(0) drain): each wave stages its own 16 rows
// x BK=16 tile of X (coalesced 64B/row), prefetching tile t+1 before the
// FMA phase of tile t so global latency hides under compute. Each thread
// computes 2 columns (c, c+OUTD/2): per k-quad 8 ds_read_b128 (<=2-way bank
// alias = free) feed 64 FMAs -> FMA-bound. W read as pre-transposed float4
// from L1 (8-32 KB, hot).
// ---------------------------------------------------------------------------
template <int K, int OUTD>
__global__ __launch_bounds__(TPB) void gemm_alpha(
    const float* __restrict__ X, const float4* __restrict__ Wt,
    const float* __restrict__ avec_src, const float* __restrict__ avec_dst,
    float* __restrict__ Hout, float* __restrict__ as_out,
    float* __restrict__ ad_out, int n) {
  constexpr int BK = 16;        // k per tile step
  constexpr int NT = K / BK;    // tile steps
  constexpr int CT = OUTD / 2;  // col-threads (each owns cols c, c+CT)
  constexpr int RG = 64 / CT;   // row groups per wave
  constexpr int RPT = 16 / RG;  // rows per thread
  constexpr int WPB = TPB / 64; // waves per block
  __shared__ float xs[WPB][2][16][BK + 4];  // row stride 20 floats (80B)

  const int t = threadIdx.x;
  const int wid = t >> 6;
  const int lane = t & 63;
  const int waveRow0 = blockIdx.x * (WPB * 16) + wid * 16;

  // staging ids: lane -> (row, k-quad); 16 rows x 4 quads = 64 lanes
  const int srow = lane >> 2;
  const int skq = lane & 3;
  const float* srcRow =
      X + (size_t)min(waveRow0 + srow, n - 1) * K + skq * 4;

  // compute ids
  const int c = lane % CT;
  const int rg = lane / CT;
  const int r0 = rg * RPT;

  const float a_s0 = avec_src[c], a_s1 = avec_src[c + CT];
  const float a_d0 = avec_dst[c], a_d1 = avec_dst[c + CT];

  float4 g = *(const float4*)srcRow;  // tile 0
  *(float4*)&xs[wid][0][srow][skq * 4] = g;

  float acc[RPT][2];
#pragma unroll
  for (int i = 0; i < RPT; ++i) acc[i][0] = acc[i][1] = 0.f;

  for (int tile = 0;;) {
    if (tile + 1 < NT)
      g = *(const float4*)(srcRow + (size_t)(tile + 1) * BK);  // prefetch
    const int buf = tile & 1;
#pragma unroll
    for (int kq = 0; kq < BK / 4; ++kq) {
      const int kqg = tile * (BK / 4) + kq;
      const float4 w0 = Wt[(size_t)kqg * OUTD + c];
      const float4 w1 = Wt[(size_t)kqg * OUTD + c + CT];
#pragma unroll
      for (int i = 0; i < RPT; ++i) {
        const float4 xv = *(const float4*)&xs[wid][buf][r0 + i][kq * 4];
        acc[i][0] = fmaf(xv.x, w0.x, acc[i][0]);
        acc[i][1] = fmaf(xv.x, w1.x, acc[i][1]);
        acc[i][0] = fmaf(xv.y, w0.y, acc[i][0]);
        acc[i][1] = fmaf(xv.y, w1.y, acc[i][1]);
        acc[i][0] = fmaf(xv.z, w0.z, acc[i][0]);
        acc[i][1] = fmaf(xv.z, w1.z, acc[i][1]);
        acc[i][0] = fmaf(xv.w, w0.w, acc[i][0]);
        acc[i][1] = fmaf(xv.w, w1.w, acc[i][1]);
      }
    }
    if (++tile == NT) break;
    *(float4*)&xs[wid][tile & 1][srow][skq * 4] = g;  // wave-private: no barrier
  }

#pragma unroll
  for (int i = 0; i < RPT; ++i) {
    const int r = waveRow0 + r0 + i;
    if (r < n) {  // uniform within the CT-lane group
      Hout[(size_t)r * OUTD + c] = acc[i][0];
      Hout[(size_t)r * OUTD + c + CT] = acc[i][1];
      float vs = acc[i][0] * a_s0 + acc[i][1] * a_s1;
      float vd = acc[i][0] * a_d0 + acc[i][1] * a_d1;
#pragma unroll
      for (int m = CT / 2; m >= 1; m >>= 1) {
        vs += __shfl_xor(vs, m);
        vd += __shfl_xor(vd, m);
      }
      if (c == 0) {
        as_out[r] = vs;
        ad_out[r] = vd;
      }
    }
  }
}

// ---------------------------------------------------------------------------
// CSR-by-dst build: count -> 3-phase exclusive scan -> fill (stores SRC
// node id directly).
// ---------------------------------------------------------------------------
__global__ void count_edges(const int* __restrict__ edst, int E, int n,
                            int* __restrict__ cnt) {
  int i = blockIdx.x * blockDim.x + threadIdx.x;
  if (i >= E + n) return;
  int d = (i < E) ? edst[i] : (i - E);
  atomicAdd(&cnt[d], 1);
}

__global__ void scan_block_sums(const int* __restrict__ in, int n,
                                int* __restrict__ sums) {
  __shared__ int sdata[TPB];
  const int base = blockIdx.x * SCAN_CHUNK;
  int s = 0;
  for (int i = threadIdx.x; i < SCAN_CHUNK; i += TPB) {
    int idx = base + i;
    s += (idx < n) ? in[idx] : 0;
  }
  sdata[threadIdx.x] = s;
  __syncthreads();
  for (int m = TPB / 2; m >= 1; m >>= 1) {
    if (threadIdx.x < m) sdata[threadIdx.x] += sdata[threadIdx.x + m];
    __syncthreads();
  }
  if (threadIdx.x == 0) sums[blockIdx.x] = sdata[0];
}

__global__ void scan_sums_exclusive(int* __restrict__ sums, int nchunks,
                                    int* __restrict__ total) {
  if (blockIdx.x == 0 && threadIdx.x == 0) {
    int run = 0;
    for (int i = 0; i < nchunks; ++i) {
      int v = sums[i];
      sums[i] = run;
      run += v;
    }
    *total = run;
  }
}

__global__ void scan_write(const int* __restrict__ in, int n,
                           const int* __restrict__ chunkOff,
                           const int* __restrict__ total,
                           int* __restrict__ rowoff) {
  __shared__ int tsum[TPB];
  const int base = blockIdx.x * SCAN_CHUNK;
  const int t = threadIdx.x;
  int v[4];
  int s = 0;
#pragma unroll
  for (int j = 0; j < 4; ++j) {
    int idx = base + t * 4 + j;
    v[j] = (idx < n) ? in[idx] : 0;
    s += v[j];
  }
  tsum[t] = s;
  __syncthreads();
  for (int off = 1; off < TPB; off <<= 1) {  // Hillis-Steele inclusive
    int x = (t >= off) ? tsum[t - off] : 0;
    __syncthreads();
    tsum[t] += x;
    __syncthreads();
  }
  int excl = ((t == 0) ? 0 : tsum[t - 1]) + chunkOff[blockIdx.x];
#pragma unroll
  for (int j = 0; j < 4; ++j) {
    int idx = base + t * 4 + j;
    if (idx < n) rowoff[idx] = excl;
    excl += v[j];
  }
  if (blockIdx.x == 0 && t == 0) rowoff[n] = *total;
}

__global__ void fill_psrc(const int* __restrict__ esrc,
                          const int* __restrict__ edst, int E, int n,
                          int* __restrict__ cursor, int* __restrict__ psrc) {
  int i = blockIdx.x * blockDim.x + threadIdx.x;
  if (i >= E + n) return;
  int d, s;
  if (i < E) {
    d = edst[i];
    s = esrc[i];
  } else {
    d = i - E;
    s = i - E;
  }
  int pos = atomicAdd(&cursor[d], 1);
  psrc[pos] = s;
}

// ---------------------------------------------------------------------------
// GAT aggregation: one wave per destination node, single-pass online softmax.
// ---------------------------------------------------------------------------
template <int D>
__global__ __launch_bounds__(TPB) void gat_aggregate(
    const float* __restrict__ Hf, const float* __restrict__ as,
    const float* __restrict__ ad, const int* __restrict__ rowoff,
    const int* __restrict__ psrc, int n, const float* __restrict__ bias,
    float* __restrict__ out, int doRelu) {
  constexpr int LPE = D / 2;     // lanes per edge (float2 each)
  constexpr int EPS = 64 / LPE;  // edges per step
  constexpr int WPB = TPB / 64;  // waves per block
  __shared__ float2 wsP[WPB][64];

  const int wave = (blockIdx.x * blockDim.x + threadIdx.x) >> 6;
  const int wid = threadIdx.x >> 6;
  const int lane = threadIdx.x & 63;
  if (wave >= n) return;
  const int i = wave;
  const int beg = rowoff[i];
  const int end = rowoff[i + 1];
  const float adi = ad[i];

  const int p = lane / LPE;          // edge phase within a step
  const int fl2 = (lane % LPE) * 2;  // feature pair base

  float m = -1e30f, denom = 0.f;
  float2 acc = make_float2(0.f, 0.f);

  for (int c = beg; c < end; c += 64) {
    const int k = c + lane;
    const bool valid = (k < end);
    int s = 0;
    float e = -1e30f;
    if (valid) {
      s = psrc[k];
      e = as[s] + adi;
      e = (e > 0.f) ? e : e * NEG_SLOPE;
    }
    // chunk max over the wave
    float cm = e;
#pragma unroll
    for (int mm = 32; mm >= 1; mm >>= 1) cm = fmaxf(cm, __shfl_xor(cm, mm));
    const float nm = fmaxf(m, cm);
    const float scale = __expf(m - nm);  // first chunk: exp(-inf) = 0
    const float w = valid ? __expf(e - nm) : 0.f;
    float ws = w;
#pragma unroll
    for (int mm = 32; mm >= 1; mm >>= 1) ws += __shfl_xor(ws, mm);
    denom = denom * scale + ws;
    acc.x *= scale;
    acc.y *= scale;
    m = nm;

    wsP[wid][lane] = make_float2(w, __int_as_float(s));  // park (w, src)

    const int cnt = min(64, end - c);
    const int nsteps = (cnt + EPS - 1) / EPS;
#pragma unroll 4
    for (int j = 0; j < nsteps; ++j) {
      const float2 p2 = wsP[wid][j * EPS + p];
      const float wj = p2.x;
      const int sj = __float_as_int(p2.y);
      const float2 hv = *(const float2*)(Hf + (size_t)sj * D + fl2);
      acc.x = fmaf(wj, hv.x, acc.x);
      acc.y = fmaf(wj, hv.y, acc.y);
    }
  }
  // fold edge-phase partials
#pragma unroll
  for (int mm = LPE; mm < 64; mm <<= 1) {
    acc.x += __shfl_xor(acc.x, mm);
    acc.y += __shfl_xor(acc.y, mm);
  }
  if (lane < LPE) {
    float2 o;
    o.x = acc.x / denom + bias[fl2];
    o.y = acc.y / denom + bias[fl2 + 1];
    if (doRelu) {
      o.x = fmaxf(o.x, 0.f);
      o.y = fmaxf(o.y, 0.f);
    }
    *(float2*)(out + (size_t)i * D + fl2) = o;
  }
}

// ---------------------------------------------------------------------------
// Decode: logits[g] = dot(z[src], z[dst]) over 32 dims.
// 8 lanes per edge, float4 per lane (coalesced 128B per row).
// ---------------------------------------------------------------------------
__global__ __launch_bounds__(TPB) void decode_kernel(
    const float* __restrict__ z, const int* __restrict__ pos,
    const int* __restrict__ neg, int ED, float* __restrict__ out) {
  const int g = (blockIdx.x * blockDim.x + threadIdx.x) >> 3;
  const int lane = threadIdx.x & 7;
  if (g >= 2 * ED) return;
  int s, d;
  if (g < ED) {
    s = pos[g];
    d = pos[ED + g];
  } else {
    s = neg[g - ED];
    d = neg[ED + (g - ED)];
  }
  const float4 a = ((const float4*)(z + (size_t)s * 32))[lane];
  const float4 b = ((const float4*)(z + (size_t)d * 32))[lane];
  float v = a.x * b.x + a.y * b.y + a.z * b.z + a.w * b.w;
#pragma unroll
  for (int mm = 4; mm >= 1; mm >>= 1) v += __shfl_xor(v, mm);
  if (lane == 0) out[g] = v;
}

// ---------------------------------------------------------------------------
extern "C" void kernel_launch(void* const* d_in, const int* in_sizes, int n_in,
                              void* d_out, int out_size, void* d_ws,
                              size_t ws_size, hipStream_t stream) {
  const int N = N_NODES;
  const float* x = (const float*)d_in[0];
  const int* ei = (const int*)d_in[1];
  const int* pe = (const int*)d_in[2];
  const int* ne = (const int*)d_in[3];
  const float* W1 = (const float*)d_in[4];
  const float* a_src1 = (const float*)d_in[5];
  const float* a_dst1 = (const float*)d_in[6];
  const float* b1 = (const float*)d_in[7];
  const float* W2 = (const float*)d_in[8];
  const float* a_src2 = (const float*)d_in[9];
  const float* a_dst2 = (const float*)d_in[10];
  const float* b2 = (const float*)d_in[11];
  float* out = (float*)d_out;

  const int E = in_sizes[1] / 2;
  const int ED = in_sizes[2] / 2;
  const int* esrc = ei;
  const int* edst = ei + E;

  // workspace carve-out (256B aligned)
  char* base = (char*)d_ws;
  size_t off = 0;
  auto alloc = [&](size_t bytes) {
    char* p = base + off;
    off = (off + bytes + 255) & ~(size_t)255;
    return p;
  };
  float* A = (float*)alloc((size_t)N * 64 * 4);  // h1, later h2
  float* B = (float*)alloc((size_t)N * 64 * 4);  // out1, later z
  float* as1 = (float*)alloc((size_t)N * 4);
  float* ad1 = (float*)alloc((size_t)N * 4);
  float* as2 = (float*)alloc((size_t)N * 4);
  float* ad2 = (float*)alloc((size_t)N * 4);
  int* cnt = (int*)alloc((size_t)N * 4);  // counts, then cursor
  int* rowoff = (int*)alloc((size_t)(N + 1) * 4);
  int* chunkSums = (int*)alloc(64 * 4);
  int* total = (int*)alloc(4);
  int* psrc = (int*)alloc((size_t)(E + N) * 4);
  float4* Wt1 = (float4*)alloc((size_t)(128 / 4) * 64 * 16);
  float4* Wt2 = (float4*)alloc((size_t)(64 / 4) * 32 * 16);

  const int nEdgesTot = E + N;
  const int edgeBlocks = (nEdgesTot + TPB - 1) / TPB;
  const int nchunks = (N + SCAN_CHUNK - 1) / SCAN_CHUNK;

  // --- W pre-transpose (tiny, once) ---
  transpose_w4<<<(32 * 64 + TPB - 1) / TPB, TPB, 0, stream>>>(W1, Wt1, 128, 64);
  transpose_w4<<<(16 * 32 + TPB - 1) / TPB, TPB, 0, stream>>>(W2, Wt2, 64, 32);

  // --- CSR build (shared by both layers) ---
  hipMemsetAsync(cnt, 0, (size_t)N * 4, stream);
  count_edges<<<edgeBlocks, TPB, 0, stream>>>(edst, E, N, cnt);
  scan_block_sums<<<nchunks, TPB, 0, stream>>>(cnt, N, chunkSums);
  scan_sums_exclusive<<<1, 64, 0, stream>>>(chunkSums, nchunks, total);
  scan_write<<<nchunks, TPB, 0, stream>>>(cnt, N, chunkSums, total, rowoff);
  hipMemcpyAsync(cnt, rowoff, (size_t)N * 4, hipMemcpyDeviceToDevice, stream);
  fill_psrc<<<edgeBlocks, TPB, 0, stream>>>(esrc, edst, E, N, cnt, psrc);

  // --- layer 1: h1 = x@W1 (+alpha dots), aggregate (+b1, relu) ---
  gemm_alpha<128, 64><<<(N + 63) / 64, TPB, 0, stream>>>(x, Wt1, a_src1,
                                                         a_dst1, A, as1, ad1, N);
  gat_aggregate<64><<<(N + 3) / 4, TPB, 0, stream>>>(A, as1, ad1, rowoff, psrc,
                                                     N, b1, B, 1);

  // --- layer 2: h2 = out1@W2 (+alpha dots), aggregate (+b2) ---
  gemm_alpha<64, 32><<<(N + 63) / 64, TPB, 0, stream>>>(B, Wt2, a_src2, a_dst2,
                                                        A, as2, ad2, N);
  gat_aggregate<32><<<(N + 3) / 4, TPB, 0, stream>>>(A, as2, ad2, rowoff, psrc,
                                                     N, b2, B, 0);

  // --- decode ---
  const long long decThreads = 2LL * ED * 8;
  decode_kernel<<<(int)((decThreads + TPB - 1) / TPB), TPB, 0, stream>>>(
      B, pe, ne, ED, out);
}

// Round 6
// 195.363 us; speedup vs baseline: 1.4924x; 1.2624x over previous
//
#include <hip/hip_runtime.h>

#define NEG_SLOPE 0.2f

constexpr int N_NODES = 50000;
constexpr int TPB = 256;
constexpr int BSH = 7;                          // 128 nodes per bucket
constexpr int NB = (N_NODES + 127) >> BSH;      // 391 buckets
constexpr int SCAT_CHUNK = 8192;

// ---------------------------------------------------------------------------
// One-shot W transpose: Wt[k4*OUTD + c] = float4(W[4k4..4k4+3][c]).
// ---------------------------------------------------------------------------
__global__ void transpose_w4(const float* __restrict__ W,
                             float4* __restrict__ Wt, int K, int OUTD) {
  int i = blockIdx.x * blockDim.x + threadIdx.x;
  if (i >= (K / 4) * OUTD) return;
  int k4 = i / OUTD, c = i % OUTD;
  Wt[i] = make_float4(W[(4 * k4 + 0) * OUTD + c], W[(4 * k4 + 1) * OUTD + c],
                      W[(4 * k4 + 2) * OUTD + c], W[(4 * k4 + 3) * OUTD + c]);
}

// ---------------------------------------------------------------------------
// GEMM + fused alpha epilogue. Wave-private double-buffered LDS pipeline,
// zero block barriers (no vmcnt(0) drain). See R4 notes.
// ---------------------------------------------------------------------------
template <int K, int OUTD>
__global__ __launch_bounds__(TPB) void gemm_alpha(
    const float* __restrict__ X, const float4* __restrict__ Wt,
    const float* __restrict__ avec_src, const float* __restrict__ avec_dst,
    float* __restrict__ Hout, float* __restrict__ as_out,
    float* __restrict__ ad_out, int n) {
  constexpr int BK = 16;         // k per tile step
  constexpr int NT = K / BK;     // tile steps
  constexpr int CT = OUTD / 2;   // col-threads (each owns cols c, c+CT)
  constexpr int RG = 64 / CT;    // row groups per wave
  constexpr int RPT = 16 / RG;   // rows per thread
  constexpr int WPB = TPB / 64;  // waves per block
  __shared__ float xs[WPB][2][16][BK + 4];  // row stride 20 floats (80B)

  const int t = threadIdx.x;
  const int wid = t >> 6;
  const int lane = t & 63;
  const int waveRow0 = blockIdx.x * (WPB * 16) + wid * 16;

  // staging ids: lane -> (row, k-quad); 16 rows x 4 quads = 64 lanes
  const int srow = lane >> 2;
  const int skq = lane & 3;
  const float* srcRow = X + (size_t)min(waveRow0 + srow, n - 1) * K + skq * 4;

  // compute ids
  const int c = lane % CT;
  const int rg = lane / CT;
  const int r0 = rg * RPT;

  const float a_s0 = avec_src[c], a_s1 = avec_src[c + CT];
  const float a_d0 = avec_dst[c], a_d1 = avec_dst[c + CT];

  float4 g = *(const float4*)srcRow;  // tile 0
  *(float4*)&xs[wid][0][srow][skq * 4] = g;

  float acc[RPT][2];
#pragma unroll
  for (int i = 0; i < RPT; ++i) acc[i][0] = acc[i][1] = 0.f;

  for (int tile = 0;;) {
    if (tile + 1 < NT)
      g = *(const float4*)(srcRow + (size_t)(tile + 1) * BK);  // prefetch
    const int buf = tile & 1;
#pragma unroll
    for (int kq = 0; kq < BK / 4; ++kq) {
      const int kqg = tile * (BK / 4) + kq;
      const float4 w0 = Wt[(size_t)kqg * OUTD + c];
      const float4 w1 = Wt[(size_t)kqg * OUTD + c + CT];
#pragma unroll
      for (int i = 0; i < RPT; ++i) {
        const float4 xv = *(const float4*)&xs[wid][buf][r0 + i][kq * 4];
        acc[i][0] = fmaf(xv.x, w0.x, acc[i][0]);
        acc[i][1] = fmaf(xv.x, w1.x, acc[i][1]);
        acc[i][0] = fmaf(xv.y, w0.y, acc[i][0]);
        acc[i][1] = fmaf(xv.y, w1.y, acc[i][1]);
        acc[i][0] = fmaf(xv.z, w0.z, acc[i][0]);
        acc[i][1] = fmaf(xv.z, w1.z, acc[i][1]);
        acc[i][0] = fmaf(xv.w, w0.w, acc[i][0]);
        acc[i][1] = fmaf(xv.w, w1.w, acc[i][1]);
      }
    }
    if (++tile == NT) break;
    *(float4*)&xs[wid][tile & 1][srow][skq * 4] = g;  // wave-private
  }

#pragma unroll
  for (int i = 0; i < RPT; ++i) {
    const int r = waveRow0 + r0 + i;
    if (r < n) {  // uniform within the CT-lane group
      Hout[(size_t)r * OUTD + c] = acc[i][0];
      Hout[(size_t)r * OUTD + c + CT] = acc[i][1];
      float vs = acc[i][0] * a_s0 + acc[i][1] * a_s1;
      float vd = acc[i][0] * a_d0 + acc[i][1] * a_d1;
#pragma unroll
      for (int m = CT / 2; m >= 1; m >>= 1) {
        vs += __shfl_xor(vs, m);
        vd += __shfl_xor(vd, m);
      }
      if (c == 0) {
        as_out[r] = vs;
        ad_out[r] = vd;
      }
    }
  }
}

// ---------------------------------------------------------------------------
// Bucketed CSR-by-dst build. Bucket = dst>>7 (128 nodes each). Pairs staged
// per bucket as packed u32 (local_dst<<16 | src), then per-bucket blocks
// build rowoff + psrc with LDS-only atomics and L2-local writes.
// ---------------------------------------------------------------------------
__global__ void bucket_hist(const int* __restrict__ edst, int E,
                            int* __restrict__ pairCnt) {
  __shared__ int h[NB];
  for (int i = threadIdx.x; i < NB; i += blockDim.x) h[i] = 0;
  __syncthreads();
  for (int i = blockIdx.x * blockDim.x + threadIdx.x; i < E;
       i += gridDim.x * blockDim.x)
    atomicAdd(&h[edst[i] >> BSH], 1);
  __syncthreads();
  for (int i = threadIdx.x; i < NB; i += blockDim.x)
    if (h[i]) atomicAdd(&pairCnt[i], h[i]);
}

// single block, 512 threads: scan bucket counts -> segment offsets
__global__ void bucket_scan(const int* __restrict__ pairCnt,
                            int* __restrict__ pairOff,
                            int* __restrict__ pairCursor,
                            int* __restrict__ csrOff, int N) {
  __shared__ int a[512], b[512];
  const int t = threadIdx.x;
  const int pc = (t < NB) ? pairCnt[t] : 0;
  const int nodes = (t < NB) ? min(128, N - (t << BSH)) : 0;
  a[t] = pc;
  b[t] = pc + nodes;
  __syncthreads();
  for (int off = 1; off < 512; off <<= 1) {
    int av = (t >= off) ? a[t - off] : 0;
    int bv = (t >= off) ? b[t - off] : 0;
    __syncthreads();
    a[t] += av;
    b[t] += bv;
    __syncthreads();
  }
  if (t < NB) {
    const int pe = a[t] - pc;  // exclusive
    pairOff[t] = pe;
    pairCursor[t] = pe;
    csrOff[t] = b[t] - (pc + nodes);
  }
  if (t == 0) {
    pairOff[NB] = a[511];
    csrOff[NB] = b[511];
  }
}

__global__ void bucket_scatter(const int* __restrict__ esrc,
                               const int* __restrict__ edst, int E,
                               int* __restrict__ pairCursor,
                               unsigned* __restrict__ stage) {
  __shared__ int h[NB], baseA[NB];
  const int base0 = blockIdx.x * SCAT_CHUNK;
  const int lim = min(E, base0 + SCAT_CHUNK);
  for (int i = threadIdx.x; i < NB; i += blockDim.x) h[i] = 0;
  __syncthreads();
  for (int i = base0 + threadIdx.x; i < lim; i += blockDim.x)
    atomicAdd(&h[edst[i] >> BSH], 1);
  __syncthreads();
  for (int i = threadIdx.x; i < NB; i += blockDim.x) {
    const int c = h[i];
    baseA[i] = c ? atomicAdd(&pairCursor[i], c) : 0;
  }
  __syncthreads();
  for (int i = threadIdx.x; i < NB; i += blockDim.x) h[i] = 0;
  __syncthreads();
  for (int i = base0 + threadIdx.x; i < lim; i += blockDim.x) {
    const int d = edst[i];
    const int s = esrc[i];
    const int bkt = d >> BSH;
    const int pos = baseA[bkt] + atomicAdd(&h[bkt], 1);
    stage[pos] = ((unsigned)(d & 127) << 16) | (unsigned)s;
  }
}

// one block per bucket: LDS count -> LDS scan -> rowoff + self + psrc scatter
__global__ void build_csr(const unsigned* __restrict__ stage,
                          const int* __restrict__ pairOff,
                          const int* __restrict__ csrOff, int N,
                          int* __restrict__ rowoff, int* __restrict__ psrc) {
  __shared__ int cnt[128], excl[128];
  const int b = blockIdx.x, t = threadIdx.x;
  const int n0 = b << BSH;
  const int nn = min(128, N - n0);
  if (t < 128) cnt[t] = (t < nn) ? 1 : 0;  // self loop pre-counted
  __syncthreads();
  const int pb = pairOff[b], pe = pairOff[b + 1];
  for (int k = pb + t; k < pe; k += blockDim.x)
    atomicAdd(&cnt[stage[k] >> 16], 1);
  __syncthreads();
  if (t < 128) excl[t] = cnt[t];
  __syncthreads();
  for (int off = 1; off < 128; off <<= 1) {
    int v = (t < 128 && t >= off) ? excl[t - off] : 0;
    __syncthreads();
    if (t < 128) excl[t] += v;
    __syncthreads();
  }
  const int cb = csrOff[b];
  if (t < 128) {
    const int ex = excl[t] - cnt[t];  // exclusive
    if (t < nn) {
      rowoff[n0 + t] = cb + ex;
      psrc[cb + ex] = n0 + t;  // self edge first
    }
    cnt[t] = ex + 1;  // cursor (self consumed one slot)
  }
  if (b == 0 && t == 0) rowoff[N] = csrOff[NB];
  __syncthreads();
  for (int k = pb + t; k < pe; k += blockDim.x) {
    const unsigned p = stage[k];
    const int ld = p >> 16;
    const int s = p & 0xFFFF;
    const int pos = cb + atomicAdd(&cnt[ld], 1);
    psrc[pos] = s;
  }
}

// ---------------------------------------------------------------------------
// GAT aggregation: one wave per destination node, single-pass online softmax.
// ---------------------------------------------------------------------------
template <int D>
__global__ __launch_bounds__(TPB) void gat_aggregate(
    const float* __restrict__ Hf, const float* __restrict__ as,
    const float* __restrict__ ad, const int* __restrict__ rowoff,
    const int* __restrict__ psrc, int n, const float* __restrict__ bias,
    float* __restrict__ out, int doRelu) {
  constexpr int LPE = D / 2;     // lanes per edge (float2 each)
  constexpr int EPS = 64 / LPE;  // edges per step
  constexpr int WPB = TPB / 64;  // waves per block
  __shared__ float2 wsP[WPB][64];

  const int wave = (blockIdx.x * blockDim.x + threadIdx.x) >> 6;
  const int wid = threadIdx.x >> 6;
  const int lane = threadIdx.x & 63;
  if (wave >= n) return;
  const int i = wave;
  const int beg = rowoff[i];
  const int end = rowoff[i + 1];
  const float adi = ad[i];

  const int p = lane / LPE;          // edge phase within a step
  const int fl2 = (lane % LPE) * 2;  // feature pair base

  float m = -1e30f, denom = 0.f;
  float2 acc = make_float2(0.f, 0.f);

  for (int c = beg; c < end; c += 64) {
    const int k = c + lane;
    const bool valid = (k < end);
    int s = 0;
    float e = -1e30f;
    if (valid) {
      s = psrc[k];
      e = as[s] + adi;
      e = (e > 0.f) ? e : e * NEG_SLOPE;
    }
    // chunk max over the wave
    float cm = e;
#pragma unroll
    for (int mm = 32; mm >= 1; mm >>= 1) cm = fmaxf(cm, __shfl_xor(cm, mm));
    const float nm = fmaxf(m, cm);
    const float scale = __expf(m - nm);  // first chunk: exp(-inf) = 0
    const float w = valid ? __expf(e - nm) : 0.f;
    float ws = w;
#pragma unroll
    for (int mm = 32; mm >= 1; mm >>= 1) ws += __shfl_xor(ws, mm);
    denom = denom * scale + ws;
    acc.x *= scale;
    acc.y *= scale;
    m = nm;

    wsP[wid][lane] = make_float2(w, __int_as_float(s));  // park (w, src)

    const int cnt = min(64, end - c);
    const int nsteps = (cnt + EPS - 1) / EPS;
#pragma unroll 4
    for (int j = 0; j < nsteps; ++j) {
      const float2 p2 = wsP[wid][j * EPS + p];
      const float wj = p2.x;
      const int sj = __float_as_int(p2.y);
      const float2 hv = *(const float2*)(Hf + (size_t)sj * D + fl2);
      acc.x = fmaf(wj, hv.x, acc.x);
      acc.y = fmaf(wj, hv.y, acc.y);
    }
  }
  // fold edge-phase partials
#pragma unroll
  for (int mm = LPE; mm < 64; mm <<= 1) {
    acc.x += __shfl_xor(acc.x, mm);
    acc.y += __shfl_xor(acc.y, mm);
  }
  if (lane < LPE) {
    float2 o;
    o.x = acc.x / denom + bias[fl2];
    o.y = acc.y / denom + bias[fl2 + 1];
    if (doRelu) {
      o.x = fmaxf(o.x, 0.f);
      o.y = fmaxf(o.y, 0.f);
    }
    *(float2*)(out + (size_t)i * D + fl2) = o;
  }
}

// ---------------------------------------------------------------------------
// Decode: logits[g] = dot(z[src], z[dst]) over 32 dims.
// 8 lanes per edge, float4 per lane (coalesced 128B per row).
// ---------------------------------------------------------------------------
__global__ __launch_bounds__(TPB) void decode_kernel(
    const float* __restrict__ z, const int* __restrict__ pos,
    const int* __restrict__ neg, int ED, float* __restrict__ out) {
  const int g = (blockIdx.x * blockDim.x + threadIdx.x) >> 3;
  const int lane = threadIdx.x & 7;
  if (g >= 2 * ED) return;
  int s, d;
  if (g < ED) {
    s = pos[g];
    d = pos[ED + g];
  } else {
    s = neg[g - ED];
    d = neg[ED + (g - ED)];
  }
  const float4 a = ((const float4*)(z + (size_t)s * 32))[lane];
  const float4 b = ((const float4*)(z + (size_t)d * 32))[lane];
  float v = a.x * b.x + a.y * b.y + a.z * b.z + a.w * b.w;
#pragma unroll
  for (int mm = 4; mm >= 1; mm >>= 1) v += __shfl_xor(v, mm);
  if (lane == 0) out[g] = v;
}

// ---------------------------------------------------------------------------
extern "C" void kernel_launch(void* const* d_in, const int* in_sizes, int n_in,
                              void* d_out, int out_size, void* d_ws,
                              size_t ws_size, hipStream_t stream) {
  const int N = N_NODES;
  const float* x = (const float*)d_in[0];
  const int* ei = (const int*)d_in[1];
  const int* pe = (const int*)d_in[2];
  const int* ne = (const int*)d_in[3];
  const float* W1 = (const float*)d_in[4];
  const float* a_src1 = (const float*)d_in[5];
  const float* a_dst1 = (const float*)d_in[6];
  const float* b1 = (const float*)d_in[7];
  const float* W2 = (const float*)d_in[8];
  const float* a_src2 = (const float*)d_in[9];
  const float* a_dst2 = (const float*)d_in[10];
  const float* b2 = (const float*)d_in[11];
  float* out = (float*)d_out;

  const int E = in_sizes[1] / 2;
  const int ED = in_sizes[2] / 2;
  const int* esrc = ei;
  const int* edst = ei + E;

  // workspace carve-out (256B aligned)
  char* base = (char*)d_ws;
  size_t off = 0;
  auto alloc = [&](size_t bytes) {
    char* p = base + off;
    off = (off + bytes + 255) & ~(size_t)255;
    return p;
  };
  float* A = (float*)alloc((size_t)N * 64 * 4);  // h1, later h2
  float* B = (float*)alloc((size_t)N * 64 * 4);  // out1, later z
  float* as1 = (float*)alloc((size_t)N * 4);
  float* ad1 = (float*)alloc((size_t)N * 4);
  float* as2 = (float*)alloc((size_t)N * 4);
  float* ad2 = (float*)alloc((size_t)N * 4);
  int* rowoff = (int*)alloc((size_t)(N + 1) * 4);
  int* psrc = (int*)alloc((size_t)(E + N) * 4);
  unsigned* stage = (unsigned*)alloc((size_t)E * 4);
  int* pairCnt = (int*)alloc((size_t)NB * 4);
  int* pairOff = (int*)alloc((size_t)(NB + 1) * 4);
  int* pairCursor = (int*)alloc((size_t)NB * 4);
  int* csrOff = (int*)alloc((size_t)(NB + 1) * 4);
  float4* Wt1 = (float4*)alloc((size_t)(128 / 4) * 64 * 16);
  float4* Wt2 = (float4*)alloc((size_t)(64 / 4) * 32 * 16);

  // --- W pre-transpose (tiny, once) ---
  transpose_w4<<<(32 * 64 + TPB - 1) / TPB, TPB, 0, stream>>>(W1, Wt1, 128, 64);
  transpose_w4<<<(16 * 32 + TPB - 1) / TPB, TPB, 0, stream>>>(W2, Wt2, 64, 32);

  // --- bucketed CSR build (shared by both layers) ---
  hipMemsetAsync(pairCnt, 0, (size_t)NB * 4, stream);
  bucket_hist<<<256, TPB, 0, stream>>>(edst, E, pairCnt);
  bucket_scan<<<1, 512, 0, stream>>>(pairCnt, pairOff, pairCursor, csrOff, N);
  bucket_scatter<<<(E + SCAT_CHUNK - 1) / SCAT_CHUNK, TPB, 0, stream>>>(
      esrc, edst, E, pairCursor, stage);
  build_csr<<<NB, TPB, 0, stream>>>(stage, pairOff, csrOff, N, rowoff, psrc);

  // --- layer 1: h1 = x@W1 (+alpha dots), aggregate (+b1, relu) ---
  gemm_alpha<128, 64><<<(N + 63) / 64, TPB, 0, stream>>>(x, Wt1, a_src1,
                                                         a_dst1, A, as1, ad1, N);
  gat_aggregate<64><<<(N + 3) / 4, TPB, 0, stream>>>(A, as1, ad1, rowoff, psrc,
                                                     N, b1, B, 1);

  // --- layer 2: h2 = out1@W2 (+alpha dots), aggregate (+b2) ---
  gemm_alpha<64, 32><<<(N + 63) / 64, TPB, 0, stream>>>(B, Wt2, a_src2, a_dst2,
                                                        A, as2, ad2, N);
  gat_aggregate<32><<<(N + 3) / 4, TPB, 0, stream>>>(A, as2, ad2, rowoff, psrc,
                                                     N, b2, B, 0);

  // --- decode ---
  const long long decThreads = 2LL * ED * 8;
  decode_kernel<<<(int)((decThreads + TPB - 1) / TPB), TPB, 0, stream>>>(
      B, pe, ne, ED, out);
}